// Round 14
// baseline (326.313 us; speedup 1.0000x reference)
//
#include <hip/hip_runtime.h>

#define TSEQ 111
#define L2E 1.44269504088896340736f
#define TWO_L2E 2.88539008177792680472f

using f32x4  = __attribute__((ext_vector_type(4))) float;
using f32x2  = __attribute__((ext_vector_type(2))) float;
using short8 = __attribute__((ext_vector_type(8))) short;

union FragU { unsigned u[4]; uint4 v; short8 s; };

__device__ __forceinline__ float fexp2(float x) { return __builtin_amdgcn_exp2f(x); }
__device__ __forceinline__ float frcp(float x)  { return __builtin_amdgcn_rcpf(x); }
// tanh(z) given zs = z*log2(e)
__device__ __forceinline__ float tanh2(float zs) { return 1.f - 2.f * frcp(1.f + fexp2(zs + zs)); }
__device__ __forceinline__ f32x2 exp2v(f32x2 x) { f32x2 r; r[0] = fexp2(x[0]); r[1] = fexp2(x[1]); return r; }
__device__ __forceinline__ f32x2 rcpv(f32x2 x)  { f32x2 r; r[0] = frcp(x[0]); r[1] = frcp(x[1]); return r; }

// round-to-nearest-even bf16, value in LOW 16 bits
__device__ __forceinline__ unsigned rnd_bf16(float w) {
  unsigned u = __float_as_uint(w);
  return (u + 0x7fffu + ((u >> 16) & 1u)) >> 16;
}
// packed f32->bf16x2 in ONE instruction
__device__ __forceinline__ unsigned cvtpk(float a, float b) {
  unsigned r;
  asm("v_cvt_pk_bf16_f32 %0, %1, %2" : "=v"(r) : "v"(a), "v"(b));
  return r;
}
__device__ __forceinline__ float uaf(unsigned u) { return __uint_as_float(u); }

// 16-WAVE BLOCK = 4 layers x 4 unit-quarters, 16 batch rows/block, 1024 threads.
// __launch_bounds__(1024,8) -> 2 blocks/CU -> 8 waves/SIMD (vs 4 before): doubled
// stream count covers the barrier-aligned ds_read/MFMA/trans latency chains.
// Wave (l,uq) owns hidden units 8uq..8uq+7 of layer l via TWO W-tiles whose rows are
// packed (gate = row&3, unit = 8uq + 2*(row>>2) + tile): C-frag elem e of lane (c,q)
// = gate e of unit (8uq+2q+tile), batch c -> lane owns ALL 4 gates of 2 ADJACENT units.
// Gate math = ONE packed f32x2 block (14 trans/lane); h-write = ONE ds_write_b32.
// hb slots (bf16 [16 batch][32 units], 16B chunks XOR-swizzled by gcc(c)=(c&3)^(c>>2)):
//   slot k = h of layer k; B-frag read = ds_read_b128 (units 8q..8q+7 of batch c).
// l0 waves build fi from emb regs (redundant x4, cheap); l3 waves redundantly compute
// the score MFMA (A = Wa replicated rows); softmax pairs score(t-1) with stashed
// hvPrev = own-units h3(t-1). xA/xB register pair is l0's emb stage AND l3's Wa frags.
// Main-loop barrier = lgkmcnt-only.
__global__ __launch_bounds__(1024, 8) void lstm_fused(
    const int* __restrict__ x, const float* __restrict__ emb,
    const float* __restrict__ Wih, const float* __restrict__ Whh,
    const float* __restrict__ bih, const float* __restrict__ bhh,
    const float* __restrict__ Wa, const float* __restrict__ W1,
    const float* __restrict__ b1, const float* __restrict__ W2,
    const float* __restrict__ b2, float* __restrict__ out)
{
  __shared__ __align__(16) unsigned short hb[2 * 4 * 512];  // [parity][slot][16][32] bf16

  const int tid  = threadIdx.x;
  const int wvu  = __builtin_amdgcn_readfirstlane(tid) >> 6;  // wave id 0..15 (SGPR)
  const int l    = wvu >> 2;       // layer 0..3
  const int uq   = wvu & 3;        // unit quarter
  const int lane = tid & 63;
  const int c    = lane & 15;      // batch row (B/C col); W-tile row (A)
  const int q    = lane >> 4;
  const int gcc  = (c & 3) ^ (c >> 2);   // chunk swizzle for row c
  const int rowbase = blockIdx.x * 16;
  const int xrow = (rowbase + c) * TSEQ;

  // lane-static LDS offsets (in shorts)
  const int rdOff = c * 32 + ((q ^ gcc) << 3);          // B-frag read
  const int wrOff = c * 32 + ((uq ^ gcc) << 3) + 2 * q; // owned-unit pair write (b32)

  // ---- weights -> 2 register A-fragments (packed rows), RTN bf16, sign/scale folded
  FragU wif[2], whf[2];
  f32x4 bvv[2];
#pragma unroll
  for (int t = 0; t < 2; ++t) {
    const int gate = c & 3;
    const float sj = (gate == 2) ? TWO_L2E : -L2E;
    const int unit = 8 * uq + 2 * (c >> 2) + t;
    const float* srcI = Wih + l * 4096 + (32 * gate + unit) * 32 + 8 * q;
    const float* srcH = Whh + l * 4096 + (32 * gate + unit) * 32 + 8 * q;
#pragma unroll
    for (int p = 0; p < 4; ++p) {
      wif[t].u[p] = rnd_bf16(srcI[2 * p] * sj) | (rnd_bf16(srcI[2 * p + 1] * sj) << 16);
      whf[t].u[p] = rnd_bf16(srcH[2 * p] * sj) | (rnd_bf16(srcH[2 * p + 1] * sj) << 16);
    }
    // bias C-operand: elem e = gate e of unit 8uq+2q+t
#pragma unroll
    for (int e = 0; e < 4; ++e) {
      const float se = (e == 2) ? TWO_L2E : -L2E;
      const int bi = l * 128 + 32 * e + 8 * uq + 2 * q + t;
      bvv[t][e] = (bih[bi] + bhh[bi]) * se;
    }
  }

  // ---- xA/xB: l0 -> emb staging regs; l3 -> Wa A-frag (hi/lo, replicated rows)
  FragU xA, xB;
#pragma unroll
  for (int p = 0; p < 4; ++p) { xA.u[p] = 0u; xB.u[p] = 0u; }
  int idxn = 0;
  if (l == 0) {
    int i0 = x[xrow];
    xA.v = *(const uint4*)(emb + i0 * 32 + 8 * q);       // floats bitcast
    xB.v = *(const uint4*)(emb + i0 * 32 + 8 * q + 4);
    idxn = x[xrow + 1];
  }
  if (l == 3) {
#pragma unroll
    for (int p = 0; p < 4; ++p) {
      const int k0 = 8 * q + 2 * p;
      float w0 = Wa[k0] * L2E, w1 = Wa[k0 + 1] * L2E;
      unsigned h0 = rnd_bf16(w0), h1b = rnd_bf16(w1);
      xA.u[p] = h0 | (h1b << 16);
      float l0v = w0 - __uint_as_float(h0 << 16);
      float l1v = w1 - __uint_as_float(h1b << 16);
      xB.u[p] = rnd_bf16(l0v) | (rnd_bf16(l1v) << 16);
    }
  }

  // per-lane state: cells + attention for owned unit pair (8uq+2q, +1), batch c
  f32x2 cs = {0.f, 0.f}, cx = {0.f, 0.f}, hvPrev = {0.f, 0.f};
  float mr = -1e30f, sr = 0.f;

  // ---- zero LDS
  for (int i = tid; i < 2 * 4 * 512 / 2; i += 1024) ((unsigned*)hb)[i] = 0u;
  __syncthreads();

#pragma unroll 2
  for (int s = 0; s < TSEQ + 4; ++s) {
    const int t = s - l;
    const bool active = ((unsigned)t < (unsigned)TSEQ);
    const int rp = (s + 1) & 1;   // read parity
    const int wp = s & 1;         // write parity
    const bool doAtt = (l == 3) && (s >= 4);

    // ---- B-fragment acquire
    FragU fi, fh;
    __builtin_amdgcn_s_setprio(1);
    if (active) {
      if (l == 0) {
        fi.u[0] = cvtpk(uaf(xA.u[0]), uaf(xA.u[1]));
        fi.u[1] = cvtpk(uaf(xA.u[2]), uaf(xA.u[3]));
        fi.u[2] = cvtpk(uaf(xB.u[0]), uaf(xB.u[1]));
        fi.u[3] = cvtpk(uaf(xB.u[2]), uaf(xB.u[3]));
        if (t + 1 < TSEQ) {
          xA.v = *(const uint4*)(emb + idxn * 32 + 8 * q);
          xB.v = *(const uint4*)(emb + idxn * 32 + 8 * q + 4);
        }
        if (t + 2 < TSEQ) idxn = x[xrow + t + 2];
      } else {
        fi.v = *(const uint4*)(hb + (rp * 4 + (l - 1)) * 512 + rdOff);
      }
    }
    if (active || doAtt)
      fh.v = *(const uint4*)(hb + (rp * 4 + l) * 512 + rdOff);

    // ---- gate MFMAs: C elem e = gate e of unit (8uq+2q+t#), batch c
    f32x4 acc0, acc1;
    if (active) {
      acc0 = __builtin_amdgcn_mfma_f32_16x16x32_bf16(wif[0].s, fi.s, bvv[0], 0, 0, 0);
      acc0 = __builtin_amdgcn_mfma_f32_16x16x32_bf16(whf[0].s, fh.s, acc0, 0, 0, 0);
      acc1 = __builtin_amdgcn_mfma_f32_16x16x32_bf16(wif[1].s, fi.s, bvv[1], 0, 0, 0);
      acc1 = __builtin_amdgcn_mfma_f32_16x16x32_bf16(whf[1].s, fh.s, acc1, 0, 0, 0);
    }
    // ---- attention score MFMAs (l=3, fh = h3(t-1) B-frag; Wa replicated rows)
    f32x4 sacc;
    if (doAtt) {
      f32x4 z = {0.f, 0.f, 0.f, 0.f};
      sacc = __builtin_amdgcn_mfma_f32_16x16x32_bf16(xA.s, fh.s, z, 0, 0, 0);
      sacc = __builtin_amdgcn_mfma_f32_16x16x32_bf16(xB.s, fh.s, sacc, 0, 0, 0);
    }
    __builtin_amdgcn_s_setprio(0);

    // ---- online-softmax update: score(t-1) paired with stashed hvPrev = h3(t-1)
    if (doAtt) {
      float pf = sacc[0];                 // score(batch c), replicated over elems
      float mn = fmaxf(mr, pf);
      float sc = fexp2(mr - mn);
      float pr = fexp2(pf - mn);
      sr = sr * sc + pr;
      cx[0] = cx[0] * sc + pr * hvPrev[0];
      cx[1] = cx[1] * sc + pr * hvPrev[1];
      mr = mn;
    }

    if (active) {
      // ---- gates (ONE packed f32x2 block): elem pair = units (8uq+2q, +1)
      // va=-zi*l2e vm=-zf*l2e vb=+2zg*l2e vp=-zo*l2e
      f32x2 va; va[0] = acc0[0]; va[1] = acc1[0];
      f32x2 vm; vm[0] = acc0[1]; vm[1] = acc1[1];
      f32x2 vb; vb[0] = acc0[2]; vb[1] = acc1[2];
      f32x2 vp; vp[0] = acc0[3]; vp[1] = acc1[3];
      const f32x2 one = {1.f, 1.f};
      f32x2 ea = exp2v(va), em_ = exp2v(vm), eb = exp2v(vb), ep = exp2v(vp);
      f32x2 P  = (one + ea) * (one + eb);
      f32x2 M1 = one + em_;
      f32x2 cn = (cs * P + (eb - one) * M1) * rcpv(M1 * P);
      cs = cn;
      f32x2 qa; qa[0] = fminf(cn[0] * TWO_L2E, 80.f); qa[1] = fminf(cn[1] * TWO_L2E, 80.f);
      f32x2 qv = exp2v(qa);
      f32x2 hvv = (qv - one) * rcpv((one + ep) * (one + qv));

      // ---- write owned unit pair of h(t): ONE ds_write_b32
      *(unsigned*)(hb + (wp * 4 + l) * 512 + wrOff) = cvtpk(hvv[0], hvv[1]);

      if (l == 3) hvPrev = hvv;
    }

    // lgkm-only barrier: LDS synced; global prefetches stay in flight
    asm volatile("s_waitcnt lgkmcnt(0)\n\ts_barrier" ::: "memory");
  }

  __syncthreads();

  // ---- context -> LDS (fp32 [16][33]); l3 wave uq, lane (c,q): units 8uq+2q, +1
  float* cb = (float*)hb;
  if (l == 3) {
    float inv = frcp(sr);
    cb[c * 33 + 8 * uq + 2 * q]     = cx[0] * inv;
    cb[c * 33 + 8 * uq + 2 * q + 1] = cx[1] * inv;
  }
  __syncthreads();
  if (wvu != 6) return;

  // ---- head (single wave): tanh MLP -> out
  float a0[4], a1[4];
  {
    float bb0 = b1[c], bb1 = b1[c + 16];
#pragma unroll
    for (int e = 0; e < 4; ++e) { a0[e] = bb0; a1[e] = bb1; }
    for (int j = 0; j < 32; ++j) {
      float w0 = W1[j * 32 + c];
      float w1 = W1[j * 32 + c + 16];
#pragma unroll
      for (int e = 0; e < 4; ++e) {
        float cr = cb[(4 * q + e) * 33 + j];
        a0[e] = fmaf(cr, w0, a0[e]);
        a1[e] = fmaf(cr, w1, a1[e]);
      }
    }
  }
  float o0[4], o1[4], o2[4];
  {
    float w20 = W2[c * 3 + 0], w21 = W2[c * 3 + 1], w22 = W2[c * 3 + 2];
    float w30 = W2[(c + 16) * 3 + 0], w31 = W2[(c + 16) * 3 + 1], w32 = W2[(c + 16) * 3 + 2];
#pragma unroll
    for (int e = 0; e < 4; ++e) {
      float h0 = tanh2(a0[e] * L2E);
      float hB = tanh2(a1[e] * L2E);
      o0[e] = h0 * w20 + hB * w30;
      o1[e] = h0 * w21 + hB * w31;
      o2[e] = h0 * w22 + hB * w32;
    }
  }
#pragma unroll
  for (int mk = 1; mk <= 8; mk <<= 1) {
#pragma unroll
    for (int e = 0; e < 4; ++e) {
      o0[e] += __shfl_xor(o0[e], mk, 64);
      o1[e] += __shfl_xor(o1[e], mk, 64);
      o2[e] += __shfl_xor(o2[e], mk, 64);
    }
  }
  if (c < 3) {
    float bb = b2[c];
#pragma unroll
    for (int e = 0; e < 4; ++e) {
      float v = (c == 0) ? o0[e] : ((c == 1) ? o1[e] : o2[e]);
      out[(rowbase + 4 * q + e) * 3 + c] = v + bb;
    }
  }
}

extern "C" void kernel_launch(void* const* d_in, const int* in_sizes, int n_in,
                              void* d_out, int out_size, void* d_ws, size_t ws_size,
                              hipStream_t stream) {
  const int*   x   = (const int*)d_in[0];
  const float* emb = (const float*)d_in[1];
  const float* Wih = (const float*)d_in[2];
  const float* Whh = (const float*)d_in[3];
  const float* bih = (const float*)d_in[4];
  const float* bhh = (const float*)d_in[5];
  const float* Wa  = (const float*)d_in[6];
  // d_in[7] = ba: softmax is shift-invariant, so ba cancels exactly
  const float* W1  = (const float*)d_in[8];
  const float* b1  = (const float*)d_in[9];
  const float* W2  = (const float*)d_in[10];
  const float* b2  = (const float*)d_in[11];
  float* out = (float*)d_out;

  lstm_fused<<<512, 1024, 0, stream>>>(x, emb, Wih, Whh, bih, bhh, Wa, W1, b1, W2, b2, out);
}

// Round 15
// 158.523 us; speedup vs baseline: 2.0585x; 2.0585x over previous
//
#include <hip/hip_runtime.h>

#define TSEQ 111
#define L2E 1.44269504088896340736f
#define TWO_L2E 2.88539008177792680472f

using f32x4  = __attribute__((ext_vector_type(4))) float;
using f32x2  = __attribute__((ext_vector_type(2))) float;
using short8 = __attribute__((ext_vector_type(8))) short;

union FragU { unsigned u[4]; uint4 v; short8 s; };

__device__ __forceinline__ float fexp2(float x) { return __builtin_amdgcn_exp2f(x); }
__device__ __forceinline__ float frcp(float x)  { return __builtin_amdgcn_rcpf(x); }
// tanh(z) given zs = z*log2(e)
__device__ __forceinline__ float tanh2(float zs) { return 1.f - 2.f * frcp(1.f + fexp2(zs + zs)); }
__device__ __forceinline__ f32x2 exp2v(f32x2 x) { f32x2 r; r[0] = fexp2(x[0]); r[1] = fexp2(x[1]); return r; }
__device__ __forceinline__ f32x2 rcpv(f32x2 x)  { f32x2 r; r[0] = frcp(x[0]); r[1] = frcp(x[1]); return r; }

// round-to-nearest-even bf16, value in LOW 16 bits
__device__ __forceinline__ unsigned rnd_bf16(float w) {
  unsigned u = __float_as_uint(w);
  return (u + 0x7fffu + ((u >> 16) & 1u)) >> 16;
}
// packed f32->bf16x2 in ONE instruction
__device__ __forceinline__ unsigned cvtpk(float a, float b) {
  unsigned r;
  asm("v_cvt_pk_bf16_f32 %0, %1, %2" : "=v"(r) : "v"(a), "v"(b));
  return r;
}

// R13 structure (best measured: 158.7 us). Block = 8 waves = 4 layers x 2 hidden-halves,
// 16 batch rows/block. SWAPPED-OPERAND gates: C = mfma(A=W-tile, B=h) -> C[unit][batch];
// lane's 4 outputs = 4 consecutive units of one batch row -> ONE ds_write_b64; store
// layout == next step's B-frag ds_read_b128 layout. 3 DS ops/wave/superstep.
// hb slots (bf16 [16 batch][32 units], 16B chunks XOR-swizzled by gcc(c)=(c&3)^(c>>2)):
//   slot k = h of layer k. Emb -> l0 B-frag regs direct from global (1 step ahead).
// Attention on l=3 pair reusing fh; per-lane scalar online softmax; zero cross-lane ops.
// Main-loop barrier = lgkmcnt-only (global prefetches stay in flight).
// l3 softmax-update (register-only) sits AFTER the barrier, overlapping the other
// waves' next-superstep ds_read phase.
__global__ __launch_bounds__(512, 4) void lstm_fused(
    const int* __restrict__ x, const float* __restrict__ emb,
    const float* __restrict__ Wih, const float* __restrict__ Whh,
    const float* __restrict__ bih, const float* __restrict__ bhh,
    const float* __restrict__ Wa, const float* __restrict__ W1,
    const float* __restrict__ b1, const float* __restrict__ W2,
    const float* __restrict__ b2, float* __restrict__ out)
{
  __shared__ __align__(16) unsigned short hb[2 * 4 * 512];  // [parity][slot][16][32] bf16

  const int tid  = threadIdx.x;
  const int wvu  = __builtin_amdgcn_readfirstlane(tid) >> 6;  // wave id 0..7 (SGPR)
  const int l    = wvu >> 1;       // layer 0..3
  const int hf   = wvu & 1;        // hidden half
  const int lane = tid & 63;
  const int c    = lane & 15;      // batch row (B/C col); W-tile row (A)
  const int q    = lane >> 4;
  const int gcc  = (c & 3) ^ (c >> 2);   // chunk swizzle for row c
  const int rowbase = blockIdx.x * 16;
  const int xrow = (rowbase + c) * TSEQ;

  // lane-static LDS offsets (in shorts)
  const int rdOff = c * 32 + ((q ^ gcc) << 3);   // B-frag read: units 8q..8q+7 of batch c
  const int wrOff = c * 32 + ((((2 * hf + (q >> 1)) ^ gcc) << 3) | ((q & 1) << 2));

  // ---- weights -> register-resident bf16 A-fragments (RTN), sign/scale folded
  FragU wihf[4], whhf[4];
#pragma unroll
  for (int g = 0; g < 4; ++g) {
    const float sj = (g == 2) ? TWO_L2E : -L2E;
    const int wr = 32 * g + 16 * hf + c;          // gate-dim row
    const float* srcI = Wih + l * 4096 + wr * 32 + 8 * q;
    const float* srcH = Whh + l * 4096 + wr * 32 + 8 * q;
#pragma unroll
    for (int p = 0; p < 4; ++p) {
      wihf[g].u[p] = rnd_bf16(srcI[2 * p] * sj) | (rnd_bf16(srcI[2 * p + 1] * sj) << 16);
      whhf[g].u[p] = rnd_bf16(srcH[2 * p] * sj) | (rnd_bf16(srcH[2 * p + 1] * sj) << 16);
    }
  }
  // biases as f32x4 C-operands: elem e = bias of unit 16hf+4q+e, gate g
  f32x4 bvv[4];
#pragma unroll
  for (int g = 0; g < 4; ++g) {
    const float sj = (g == 2) ? TWO_L2E : -L2E;
    const int bi = l * 128 + 32 * g + 16 * hf + 4 * q;
#pragma unroll
    for (int e = 0; e < 4; ++e)
      bvv[g][e] = (bih[bi + e] + bhh[bi + e]) * sj;
  }

  // ---- Wa as A-frag replicated over rows (l==3 waves), hi/lo split, scaled by log2e
  FragU wahA, walA;
#pragma unroll
  for (int p = 0; p < 4; ++p) { wahA.u[p] = 0u; walA.u[p] = 0u; }
  if (l == 3) {
#pragma unroll
    for (int p = 0; p < 4; ++p) {
      const int k0 = 8 * q + 2 * p;
      float w0 = Wa[k0] * L2E, w1 = Wa[k0 + 1] * L2E;
      unsigned h0 = rnd_bf16(w0), h1b = rnd_bf16(w1);
      wahA.u[p] = h0 | (h1b << 16);
      float l0v = w0 - __uint_as_float(h0 << 16);
      float l1v = w1 - __uint_as_float(h1b << 16);
      walA.u[p] = rnd_bf16(l0v) | (rnd_bf16(l1v) << 16);
    }
  }

  // per-lane state: cells for units 16hf+4q+e, batch c; attention (l==3)
  f32x2 cs2[2];
  cs2[0] = (f32x2){0.f, 0.f}; cs2[1] = (f32x2){0.f, 0.f};
  float mr = -1e30f, sr = 0.f, cx[4];
#pragma unroll
  for (int e = 0; e < 4; ++e) cx[e] = 0.f;

  // ---- zero LDS
  for (int i = tid; i < 2 * 4 * 512 / 2; i += 512) ((unsigned*)hb)[i] = 0u;

  // ---- l0 prologue: emb(0) -> regs; idxn = token(1)
  float4 emA = make_float4(0.f, 0.f, 0.f, 0.f), emB = emA;
  int idxn = 0;
  if (l == 0) {
    int i0 = x[xrow];
    emA = *(const float4*)(emb + i0 * 32 + 8 * q);
    emB = *(const float4*)(emb + i0 * 32 + 8 * q + 4);
    idxn = x[xrow + 1];
  }
  __syncthreads();

#pragma unroll 2
  for (int s = 0; s < TSEQ + 4; ++s) {
    const int t = s - l;
    const bool active = ((unsigned)t < (unsigned)TSEQ);
    const int rp = (s + 1) & 1;   // read parity
    const int wp = s & 1;         // write parity
    const bool doAtt = (l == 3) && (s >= 4);

    // ---- B-fragment acquire
    FragU fi, fh;
    __builtin_amdgcn_s_setprio(1);
    if (active) {
      if (l == 0) {
        // build fi from prefetched emb regs; then issue loads for t+1
        fi.u[0] = cvtpk(emA.x, emA.y); fi.u[1] = cvtpk(emA.z, emA.w);
        fi.u[2] = cvtpk(emB.x, emB.y); fi.u[3] = cvtpk(emB.z, emB.w);
        if (t + 1 < TSEQ) {
          emA = *(const float4*)(emb + idxn * 32 + 8 * q);
          emB = *(const float4*)(emb + idxn * 32 + 8 * q + 4);
        }
        if (t + 2 < TSEQ) idxn = x[xrow + t + 2];
      } else {
        fi.v = *(const uint4*)(hb + (rp * 4 + (l - 1)) * 512 + rdOff);
      }
    }
    if (active || doAtt)
      fh.v = *(const uint4*)(hb + (rp * 4 + l) * 512 + rdOff);

    // ---- gate MFMAs: C[gate-unit][batch] = W*x + W*h + bias
    f32x4 acc[4];
    if (active) {
#pragma unroll
      for (int g = 0; g < 4; ++g) {
        acc[g] = __builtin_amdgcn_mfma_f32_16x16x32_bf16(wihf[g].s, fi.s, bvv[g], 0, 0, 0);
        acc[g] = __builtin_amdgcn_mfma_f32_16x16x32_bf16(whhf[g].s, fh.s, acc[g], 0, 0, 0);
      }
    }
    // ---- attention score MFMAs (l=3, reuses fh = h3(t-1) B-frag)
    f32x4 sacc;
    if (doAtt) {
      f32x4 z = {0.f, 0.f, 0.f, 0.f};
      sacc = __builtin_amdgcn_mfma_f32_16x16x32_bf16(wahA.s, fh.s, z, 0, 0, 0);
      sacc = __builtin_amdgcn_mfma_f32_16x16x32_bf16(walA.s, fh.s, sacc, 0, 0, 0);
    }
    __builtin_amdgcn_s_setprio(0);

    if (active) {
      // ---- gates (packed f32): acc0=-zi*l2e acc1=-zf*l2e acc2=+2zg*l2e acc3=-zo*l2e
      float hv[4];
      const f32x2 one = {1.f, 1.f};
      const f32x2 tl2 = {TWO_L2E, TWO_L2E};
#pragma unroll
      for (int pr2 = 0; pr2 < 2; ++pr2) {
        const int e0 = 2 * pr2;
        f32x2 va; va[0] = acc[0][e0]; va[1] = acc[0][e0 + 1];
        f32x2 vm; vm[0] = acc[1][e0]; vm[1] = acc[1][e0 + 1];
        f32x2 vb; vb[0] = acc[2][e0]; vb[1] = acc[2][e0 + 1];
        f32x2 vp; vp[0] = acc[3][e0]; vp[1] = acc[3][e0 + 1];
        f32x2 ea = exp2v(va), em_ = exp2v(vm), eb = exp2v(vb), ep = exp2v(vp);
        f32x2 P  = (one + ea) * (one + eb);
        f32x2 M1 = one + em_;
        f32x2 num = cs2[pr2] * P + (eb - one) * M1;
        f32x2 cn = num * rcpv(M1 * P);
        cs2[pr2] = cn;
        f32x2 qa = cn * tl2;
        qa[0] = fminf(qa[0], 80.f); qa[1] = fminf(qa[1], 80.f);
        f32x2 qv = exp2v(qa);
        f32x2 hvv = (qv - one) * rcpv((one + ep) * (one + qv));
        hv[e0] = hvv[0]; hv[e0 + 1] = hvv[1];
      }

      // ---- write h(t): units 16hf+4q..+3 of batch c -> ONE ds_write_b64
      *(uint2*)(hb + (wp * 4 + l) * 512 + wrOff) =
          make_uint2(cvtpk(hv[0], hv[1]), cvtpk(hv[2], hv[3]));
    }

    // lgkm-only barrier: LDS synced; global prefetches stay in flight
    asm volatile("s_waitcnt lgkmcnt(0)\n\ts_barrier" ::: "memory");

    // ---- attention online-softmax update: register-only, AFTER the barrier so the
    // l3 straggler tail overlaps the other waves' next-superstep ds_read phase.
    if (doAtt) {
      float pf = sacc[0];
      float mn = fmaxf(mr, pf);
      float sc = fexp2(mr - mn);
      float pr = fexp2(pf - mn);
      sr = sr * sc + pr;
      // this wave accumulates units 8q + 4hf .. +3 (elems 2hf,2hf+1 of fh)
#pragma unroll
      for (int p = 0; p < 2; ++p) {
        unsigned w = fh.u[2 * hf + p];
        cx[2 * p]     = cx[2 * p]     * sc + pr * __uint_as_float(w << 16);
        cx[2 * p + 1] = cx[2 * p + 1] * sc + pr * __uint_as_float(w & 0xffff0000u);
      }
      mr = mn;
    }
  }

  __syncthreads();

  // ---- context -> LDS (fp32 [16][33]); l=3 waves: batch c, units 8q+4hf+e
  float* cb = (float*)hb;
  if (l == 3) {
    float inv = frcp(sr);
#pragma unroll
    for (int e = 0; e < 4; ++e)
      cb[c * 33 + 8 * q + 4 * hf + e] = cx[e] * inv;
  }
  __syncthreads();
  if (wvu != 6) return;

  // ---- head (single wave): tanh MLP -> out
  float a0[4], a1[4];
  {
    float bb0 = b1[c], bb1 = b1[c + 16];
#pragma unroll
    for (int e = 0; e < 4; ++e) { a0[e] = bb0; a1[e] = bb1; }
    for (int j = 0; j < 32; ++j) {
      float w0 = W1[j * 32 + c];
      float w1 = W1[j * 32 + c + 16];
#pragma unroll
      for (int e = 0; e < 4; ++e) {
        float cr = cb[(4 * q + e) * 33 + j];
        a0[e] = fmaf(cr, w0, a0[e]);
        a1[e] = fmaf(cr, w1, a1[e]);
      }
    }
  }
  float o0[4], o1[4], o2[4];
  {
    float w20 = W2[c * 3 + 0], w21 = W2[c * 3 + 1], w22 = W2[c * 3 + 2];
    float w30 = W2[(c + 16) * 3 + 0], w31 = W2[(c + 16) * 3 + 1], w32 = W2[(c + 16) * 3 + 2];
#pragma unroll
    for (int e = 0; e < 4; ++e) {
      float h0 = tanh2(a0[e] * L2E);
      float hB = tanh2(a1[e] * L2E);
      o0[e] = h0 * w20 + hB * w30;
      o1[e] = h0 * w21 + hB * w31;
      o2[e] = h0 * w22 + hB * w32;
    }
  }
#pragma unroll
  for (int mk = 1; mk <= 8; mk <<= 1) {
#pragma unroll
    for (int e = 0; e < 4; ++e) {
      o0[e] += __shfl_xor(o0[e], mk, 64);
      o1[e] += __shfl_xor(o1[e], mk, 64);
      o2[e] += __shfl_xor(o2[e], mk, 64);
    }
  }
  if (c < 3) {
    float bb = b2[c];
#pragma unroll
    for (int e = 0; e < 4; ++e) {
      float v = (c == 0) ? o0[e] : ((c == 1) ? o1[e] : o2[e]);
      out[(rowbase + 4 * q + e) * 3 + c] = v + bb;
    }
  }
}

extern "C" void kernel_launch(void* const* d_in, const int* in_sizes, int n_in,
                              void* d_out, int out_size, void* d_ws, size_t ws_size,
                              hipStream_t stream) {
  const int*   x   = (const int*)d_in[0];
  const float* emb = (const float*)d_in[1];
  const float* Wih = (const float*)d_in[2];
  const float* Whh = (const float*)d_in[3];
  const float* bih = (const float*)d_in[4];
  const float* bhh = (const float*)d_in[5];
  const float* Wa  = (const float*)d_in[6];
  // d_in[7] = ba: softmax is shift-invariant, so ba cancels exactly
  const float* W1  = (const float*)d_in[8];
  const float* b1  = (const float*)d_in[9];
  const float* W2  = (const float*)d_in[10];
  const float* b2  = (const float*)d_in[11];
  float* out = (float*)d_out;

  lstm_fused<<<512, 512, 0, stream>>>(x, emb, Wih, Whh, bih, bhh, Wa, W1, b1, W2, b2, out);
}